// Round 7
// baseline (35.878 us; speedup 1.0000x reference)
//
#include <hip/hip_runtime.h>
#include <hip/hip_bf16.h>

// AdaGuidedFilter: x:(4,64,256,256) f32 -> out same shape.
// out = x * (A*x + (1-A)*mean), A = var/(var+eps),
// mean/var from 11x11 zero-padded box sums normalized by in-window count.
//
// R7: TILE_H=32 strips (grid 2048 = 8 blocks/CU x 1 round), ring-11 vertical
// accumulator, 4 chunks of 8 rows through a 16 KB XOR-swizzled LDS buffer.
// Default launch bounds (forced (256,8) clamps VGPR to 32 and spills - R4/R5).
// Halo read amplification 2.25x -> 1.31x vs R6.

#define RAD    5
#define KW     11
#define IMG_H  256
#define IMG_W  256
#define TILE_H 32
#define CHUNK  8
#define NCHUNK (TILE_H / CHUNK)     // 4
#define STRIPS (IMG_H / TILE_H)     // 8
#define NBLK   (256 * STRIPS)       // 2048
#define EPS_F  0.01f

__device__ __forceinline__ float ldrow(const float* __restrict__ xim, int g, int c) {
    // g is block-uniform -> scalar branch
    return (g >= 0 && g < IMG_H) ? xim[(size_t)g * IMG_W + c] : 0.0f;
}

__device__ __forceinline__ void half_pass(const float2* __restrict__ vsum,
                                          float* __restrict__ oim,
                                          const float* xv,
                                          int lr, int seg, int c0, int gr) {
    const int rlo = (gr - RAD < 0) ? 0 : gr - RAD;
    const int rhi = (gr + RAD > IMG_H - 1) ? IMG_H - 1 : gr + RAD;
    const float rcnt = (float)(rhi - rlo + 1);

    float o[8];
    if (seg >= 1 && seg <= 30) {
        // interior: no column bounds, window width constant 11 -> one rcp
        float s = 0.0f, s2 = 0.0f;
        #pragma unroll
        for (int dd = -RAD; dd <= RAD; ++dd) {
            const float2 v = vsum[(lr << 8) | ((c0 + dd) ^ lr)];
            s += v.x; s2 += v.y;
        }
        const float inv = __builtin_amdgcn_rcpf(rcnt * 11.0f);
        #pragma unroll
        for (int i = 0; i < 8; ++i) {
            const float mean = s * inv;
            const float m2   = s2 * inv;
            const float var  = fmaf(-mean, mean, m2);
            const float A    = var * __builtin_amdgcn_rcpf(var + EPS_F);
            const float xq   = xv[i];
            o[i] = xq * fmaf(A, xq - mean, mean);
            if (i < 7) {
                const float2 va = vsum[(lr << 8) | ((c0 + i + RAD + 1) ^ lr)];
                const float2 vb = vsum[(lr << 8) | ((c0 + i - RAD) ^ lr)];
                s  += va.x - vb.x;
                s2 += va.y - vb.y;
            }
        }
    } else {
        float s = 0.0f, s2 = 0.0f;
        #pragma unroll
        for (int dd = -RAD; dd <= RAD; ++dd) {
            const int cc = c0 + dd;
            if (cc >= 0 && cc < IMG_W) {
                const float2 v = vsum[(lr << 8) | (cc ^ lr)];
                s += v.x; s2 += v.y;
            }
        }
        #pragma unroll
        for (int i = 0; i < 8; ++i) {
            const int c   = c0 + i;
            const int wlo = (c - RAD < 0) ? 0 : c - RAD;
            const int whi = (c + RAD > IMG_W - 1) ? IMG_W - 1 : c + RAD;
            const float inv  = __builtin_amdgcn_rcpf(rcnt * (float)(whi - wlo + 1));
            const float mean = s * inv;
            const float m2   = s2 * inv;
            const float var  = fmaf(-mean, mean, m2);
            const float A    = var * __builtin_amdgcn_rcpf(var + EPS_F);
            const float xq   = xv[i];
            o[i] = xq * fmaf(A, xq - mean, mean);
            if (i < 7) {
                const int ca = c + RAD + 1;
                const int cs = c - RAD;
                if (ca < IMG_W) { const float2 v = vsum[(lr << 8) | (ca ^ lr)]; s += v.x; s2 += v.y; }
                if (cs >= 0)    { const float2 v = vsum[(lr << 8) | (cs ^ lr)]; s -= v.x; s2 -= v.y; }
            }
        }
    }

    float4* orow = reinterpret_cast<float4*>(oim + (size_t)gr * IMG_W + c0);
    orow[0] = make_float4(o[0], o[1], o[2], o[3]);
    orow[1] = make_float4(o[4], o[5], o[6], o[7]);
}

template<bool CHECKED>
__device__ __forceinline__ void run_strip(const float* __restrict__ xim,
                                          float* __restrict__ oim,
                                          float2* __restrict__ vsum,
                                          int strip, int tid) {
    const int row0 = strip * TILE_H - RAD;
    const int lr   = tid & 7;
    const int seg  = tid >> 3;
    const int c0   = seg * 8;

    // ring of the 11 rows currently in the vertical window (static indices)
    float ring[KW];
    #pragma unroll
    for (int i = 0; i < KW; ++i)
        ring[i] = CHECKED ? ldrow(xim, row0 + i, tid)
                          : xim[(size_t)(row0 + i) * IMG_W + tid];

    float s = 0.0f, s2 = 0.0f;
    #pragma unroll
    for (int i = 0; i < KW; ++i) { s += ring[i]; s2 = fmaf(ring[i], ring[i], s2); }

    #pragma unroll
    for (int k = 0; k < NCHUNK; ++k) {
        // P1: write 8 rows of vertical sums, sliding the ring
        #pragma unroll
        for (int rr = 0; rr < CHUNK; ++rr) {
            const int r = k * CHUNK + rr;          // output row in strip, 0..31
            vsum[(rr << 8) | (tid ^ rr)] = make_float2(s, s2);
            if (r < TILE_H - 1) {
                const float old = ring[r % KW];
                const float a   = CHECKED ? ldrow(xim, row0 + KW + r, tid)
                                          : xim[(size_t)(row0 + KW + r) * IMG_W + tid];
                s  += a - old;
                s2  = fmaf(a, a, fmaf(-old, old, s2));
                ring[r % KW] = a;
            }
        }

        // epilogue x for this chunk: issue before the barrier, consume after
        const int gr = strip * TILE_H + k * CHUNK + lr;
        float xv[8];
        {
            const float4* p = reinterpret_cast<const float4*>(xim + (size_t)gr * IMG_W + c0);
            const float4 q0 = p[0], q1 = p[1];
            xv[0]=q0.x; xv[1]=q0.y; xv[2]=q0.z; xv[3]=q0.w;
            xv[4]=q1.x; xv[5]=q1.y; xv[6]=q1.z; xv[7]=q1.w;
        }

        __syncthreads();
        half_pass(vsum, oim, xv, lr, seg, c0, gr);
        if (k < NCHUNK - 1) __syncthreads();
    }
}

__global__ __launch_bounds__(256)
void AdaGuidedFilter_17686675325295_kernel(const float* __restrict__ x,
                                           float* __restrict__ out) {
    __shared__ float2 vsum[CHUNK * IMG_W];   // 16384 B

    // XCD-chunked swizzle (2048 % 8 == 0 -> bijective): each XCD gets 32
    // consecutive images (all strips) -> halo rows shared in that XCD's L2.
    const int d     = blockIdx.x;
    const int L     = (d & 7) * (NBLK / 8) + (d >> 3);
    const int img   = L >> 3;            // 0..255
    const int strip = L & (STRIPS - 1);  // 0..7
    const int tid   = threadIdx.x;

    const float* __restrict__ xim = x   + (size_t)img * (IMG_H * IMG_W);
    float* __restrict__       oim = out + (size_t)img * (IMG_H * IMG_W);

    if (strip != 0 && strip != STRIPS - 1)
        run_strip<false>(xim, oim, vsum, strip, tid);
    else
        run_strip<true>(xim, oim, vsum, strip, tid);
}

extern "C" void kernel_launch(void* const* d_in, const int* in_sizes, int n_in,
                              void* d_out, int out_size, void* d_ws, size_t ws_size,
                              hipStream_t stream) {
    (void)in_sizes; (void)n_in; (void)d_ws; (void)ws_size; (void)out_size;
    const float* x = (const float*)d_in[0];
    float* out = (float*)d_out;
    dim3 grid(NBLK);    // 2048 blocks
    dim3 block(256);
    AdaGuidedFilter_17686675325295_kernel<<<grid, block, 0, stream>>>(x, out);
}